// Round 10
// baseline (2212.739 us; speedup 1.0000x reference)
//
#include <hip/hip_runtime.h>
#include <hip/hip_bf16.h>

// LSTM: B=64, T=512, V=32000, E=256, H=512, O=1
// R10 = R9 (dual-protocol tagged exchange, 8 domains x 8 blocks x 256 thr,
// xg pre-pass) + three fixes:
//  (a) B1/B2 are raw s_barrier with lgkmcnt-only drains -> the xg prefetch
//      and publish stores stay in flight across barriers (T4 idiom); the
//      only vmcnt(0) per step is the poll's, where xg is already landed.
//  (b) dead MFMA rows 8..15 (only 8 real batches): kgrp>=2 threads skip
//      xg loads/seeds and P_lds writes (halves xg vmem).
//  (c) slow-probe cadence 4 -> 8 while spinning (less MALL traffic).
#define TB 512
#define NB 64
#define EE 256
#define HH 512
#define ND 8           // sync domains
#define DB 8           // batches per domain
#define NBLK 8         // blocks per domain
#define NT 256         // threads per block (4 waves)
#define NCOLP 260      // P_lds padded row (floats)
#define NPAIR 256      // h pairs per batch
#define GCOLS 2048
#define SLOWOFF ((size_t)0x40000)  // slow buffer offset (fast at 0, 256KB each)
#define XGOFF   ((size_t)1 << 20)  // xg offset in d_ws

typedef __bf16 bf16_t;
typedef bf16_t bf16x8 __attribute__((ext_vector_type(8)));
typedef float  f32x4  __attribute__((ext_vector_type(4)));
typedef unsigned u32;
typedef unsigned long long u64;
typedef u32 u32x4 __attribute__((ext_vector_type(4)));

__device__ __forceinline__ float sigf(float x) { return 1.0f / (1.0f + __expf(-x)); }
__device__ __forceinline__ float tanhfast(float x) {
    float xc = fminf(fmaxf(x, -15.0f), 15.0f);
    float e  = __expf(2.0f * xc);
    return (e - 1.0f) / (e + 1.0f);
}
__device__ __forceinline__ u32 bfbits(float f) {
    bf16_t h = (bf16_t)f;
    return (u32)__builtin_bit_cast(unsigned short, h);
}
__device__ __forceinline__ bf16x8 cvt8(float4 a, float4 b) {
    bf16x8 v;
    v[0]=(bf16_t)a.x; v[1]=(bf16_t)a.y; v[2]=(bf16_t)a.z; v[3]=(bf16_t)a.w;
    v[4]=(bf16_t)b.x; v[5]=(bf16_t)b.y; v[6]=(bf16_t)b.z; v[7]=(bf16_t)b.w;
    return v;
}
__device__ __forceinline__ f32x4 cvtxg(u64 v) {
    f32x4 r;
    r[0] = __uint_as_float((u32)( v        & 0xFFFFu) << 16);
    r[1] = __uint_as_float((u32)((v >> 16) & 0xFFFFu) << 16);
    r[2] = __uint_as_float((u32)((v >> 32) & 0xFFFFu) << 16);
    r[3] = __uint_as_float((u32)((v >> 48) & 0xFFFFu) << 16);
    return r;
}

// LDS-only barrier: drains DS ops, leaves vmem (xg prefetch, publish stores)
// in flight across the barrier.  sched_barrier fences compiler motion
// (rule: inline-asm waitcnt needs a sched fence or hipcc hoists past it).
__device__ __forceinline__ void bar_lds() {
    __builtin_amdgcn_sched_barrier(0);
    asm volatile("s_waitcnt lgkmcnt(0)" ::: "memory");
    __builtin_amdgcn_s_barrier();
    __builtin_amdgcn_sched_barrier(0);
}

// Dual poll of 8 tagged u64s (64B): hot-spin sc0 (L2), slow probe every 8th.
__device__ __forceinline__ void poll8_dual(const u64* fsrc, const u64* ssrc,
                                           u32 tag, u64 (&pk)[4]) {
    u64 fa = (u64)fsrc;
    int it = 0;
    for (;;) {
        u32x4 q0, q1, q2, q3;
        asm volatile(
            "global_load_dwordx4 %0, %4, off sc0\n\t"
            "global_load_dwordx4 %1, %4, off offset:16 sc0\n\t"
            "global_load_dwordx4 %2, %4, off offset:32 sc0\n\t"
            "global_load_dwordx4 %3, %4, off offset:48 sc0\n\t"
            "s_waitcnt vmcnt(0)"
            : "=&v"(q0), "=&v"(q1), "=&v"(q2), "=&v"(q3)
            : "v"(fa)
            : "memory");
        if (q0[1]==tag && q0[3]==tag && q1[1]==tag && q1[3]==tag &&
            q2[1]==tag && q2[3]==tag && q3[1]==tag && q3[3]==tag) {
            pk[0] = (u64)q0[0] | ((u64)q0[2] << 32);
            pk[1] = (u64)q1[0] | ((u64)q1[2] << 32);
            pk[2] = (u64)q2[0] | ((u64)q2[2] << 32);
            pk[3] = (u64)q3[0] | ((u64)q3[2] << 32);
            return;
        }
        if (((++it) & 7) == 0) {
            u64 hv[8];
            #pragma unroll
            for (int j = 0; j < 8; ++j)
                hv[j] = __hip_atomic_load(ssrc + j, __ATOMIC_RELAXED, __HIP_MEMORY_SCOPE_AGENT);
            bool ok = true;
            #pragma unroll
            for (int j = 0; j < 8; ++j) ok &= ((u32)(hv[j] >> 32) == tag);
            if (ok) {
                #pragma unroll
                for (int k = 0; k < 4; ++k)
                    pk[k] = (u64)(u32)hv[2*k] | ((u64)(u32)hv[2*k + 1] << 32);
                return;
            }
        }
    }
}

// ---------------- Phase 1: xg pre-pass GEMM (proven R7, verbatim) ----------------
__global__ __launch_bounds__(256, 1)
void xg_prepass(const int* __restrict__ words, const float* __restrict__ emb,
                const float* __restrict__ Wi, const float* __restrict__ bi,
                const float* __restrict__ bh, bf16_t* __restrict__ xgT)
{
    const int tid = threadIdx.x, lane = tid & 63, wv = tid >> 6;
    const int kgrp = lane >> 4, cl = lane & 15;
    const int cc = blockIdx.x & 7, tc = blockIdx.x >> 3;

    __shared__ __align__(16) bf16_t x_s[64][EE];

    bf16x8 wf[8][4];
    float  bv[4];
    #pragma unroll
    for (int nt = 0; nt < 4; ++nt) {
        int col = cc*256 + wv*64 + nt*16 + cl;
        int wrow = (col & 3)*HH + (col >> 2);
        const float* wr = Wi + (size_t)wrow*EE;
        #pragma unroll
        for (int kt = 0; kt < 8; ++kt) {
            const float4* p = (const float4*)(wr + kt*32 + kgrp*8);
            wf[kt][nt] = cvt8(p[0], p[1]);
        }
        bv[nt] = bi[wrow] + bh[wrow];
    }

    const int r0 = tid >> 2, q = tid & 3;
    const int swz = (r0 & 7) << 3;
    u64* dst = (u64*)xgT;

    for (int it = 0; it < 16; ++it) {
        int t = tc*16 + it;
        {
            int wd = words[r0*TB + t];
            const float4* p = (const float4*)(emb + (size_t)wd*EE + q*64);
            #pragma unroll
            for (int o = 0; o < 8; ++o) {
                float4 a = p[2*o], b2 = p[2*o + 1];
                *(bf16x8*)&x_s[r0][(q*64 + o*8) ^ swz] = cvt8(a, b2);
            }
        }
        __syncthreads();

        f32x4 acc[4][4];
        #pragma unroll
        for (int rt = 0; rt < 4; ++rt)
            #pragma unroll
            for (int nt = 0; nt < 4; ++nt)
                acc[rt][nt] = (f32x4){ bv[nt], bv[nt], bv[nt], bv[nt] };
        #pragma unroll
        for (int kt = 0; kt < 8; ++kt) {
            #pragma unroll
            for (int rt = 0; rt < 4; ++rt) {
                bf16x8 a = *(const bf16x8*)&x_s[rt*16 + cl][(kt*32 + kgrp*8) ^ ((cl & 7) << 3)];
                #pragma unroll
                for (int nt = 0; nt < 4; ++nt)
                    acc[rt][nt] = __builtin_amdgcn_mfma_f32_16x16x32_bf16(a, wf[kt][nt], acc[rt][nt], 0, 0, 0);
            }
        }
        #pragma unroll
        for (int nt = 0; nt < 4; ++nt) {
            int col = cc*256 + wv*64 + nt*16 + cl;
            #pragma unroll
            for (int rt = 0; rt < 4; ++rt) {
                f32x4 v = acc[rt][nt];
                u64 pkk =  (u64)(bfbits(v[0]))
                        | ((u64)(bfbits(v[1])) << 16)
                        | ((u64)(bfbits(v[2])) << 32)
                        | ((u64)(bfbits(v[3])) << 48);
                dst[(size_t)(t*GCOLS + col)*16 + rt*4 + kgrp] = pkk;
            }
        }
        __syncthreads();
    }
}

// ---------------- Phase 2: persistent recurrence ----------------
__global__ __launch_bounds__(NT, 1)
void lstm_main(const float* __restrict__ Wh,
               const float* __restrict__ Wfc,
               const float* __restrict__ bfc,
               float* __restrict__ out,        // [64] head + [64*512] h (fp32)
               u64* __restrict__ fastH,        // [2][NB][NPAIR] tagged pairs (sc0)
               u64* __restrict__ slowH,        // [2][NB][NPAIR] tagged pairs (agent)
               const u64* __restrict__ xg64)   // xg[t][col][batchquad]
{
    const int tid  = threadIdx.x;
    const int lane = tid & 63;
    const int wv   = tid >> 6;        // 0..3
    const int g    = blockIdx.x & 7;  // domain (-> one XCD under round-robin)
    const int ug   = blockIdx.x >> 3; // unit group 0..7 (64 units each)
    const int kgrp = lane >> 4;
    const int cl   = lane & 15;

    __shared__ __align__(16) bf16_t h_lds[16][HH];    // rows 8..15 stay zero
    __shared__ __align__(16) float  P_lds[16][NCOLP];

    // zero h_lds (h_{-1}=0)
    for (int i = tid; i < 16*HH/2; i += NT) ((u32*)h_lds)[i] = 0u;

    // ---- Wh fragments: 4 n-tiles per wave (256 local cols per block) ----
    bf16x8 whf[16][4];
    #pragma unroll
    for (int nt = 0; nt < 4; ++nt) {
        int gc = ug*256 + wv*64 + nt*16 + cl;       // global gate-col
        int wrow = (gc & 3)*HH + (gc >> 2);
        const float* wr = Wh + (size_t)wrow*HH;
        #pragma unroll
        for (int kt = 0; kt < 16; ++kt) {
            const float4* p = (const float4*)(wr + kt*32 + kgrp*8);
            whf[kt][nt] = cvt8(p[0], p[1]);
        }
    }

    // thread roles for poll/act: batch sb (0..7), chunk sc (0..31)
    const int sb = tid >> 5, sc = tid & 31;
    const int swz = sb << 3;

    // xg: only kgrp<2 rows are real batches (D rows 0..7); kgrp>=2 dead
    const bool xlive = (kgrp < 2);
    const int m = 2*g + kgrp;                   // valid when xlive
    int gc[4];
    #pragma unroll
    for (int nt = 0; nt < 4; ++nt) gc[nt] = ug*256 + wv*64 + nt*16 + cl;

    u64 xgc[4] = {0,0,0,0}, xgn[4] = {0,0,0,0};
    if (xlive) {
        #pragma unroll
        for (int nt = 0; nt < 4; ++nt) xgc[nt] = xg64[(size_t)gc[nt]*16 + m];
    }

    float c0 = 0.f, c1 = 0.f;
    __syncthreads();   // full barrier once (h_lds zeros + weight loads settled)

    for (int t = 0; t < TB; ++t) {
        // ---- poll tagged h_{t-1} (8 pairs from one producer), stage to LDS ----
        if (t > 0) {
            size_t off = ((size_t)((t & 1) ^ 1))*NB*NPAIR
                       + (size_t)(g*DB + sb)*NPAIR + sc*8;
            u64 pk[4];
            poll8_dual(fastH + off, slowH + off, (u32)t, pk);
            #pragma unroll
            for (int k = 0; k < 4; ++k) {
                int e = sc*16 + 4*k;
                int phys = ((e & ~7) ^ swz) | (e & 7);
                *(u64*)&h_lds[sb][phys] = pk[k];
            }
        }

        // ---- prefetch xg(t+1): stays in flight across bar_lds (no vm drain);
        //      landed by the time next step's poll does vmcnt(0) ----
        if (xlive && t + 1 < TB) {
            #pragma unroll
            for (int nt = 0; nt < 4; ++nt)
                xgn[nt] = xg64[(size_t)((t + 1)*GCOLS + gc[nt])*16 + m];
        }
        bar_lds();   // B1: h_lds visible (DS-only drain)

        // ---- recurrent MFMAs, rows 0..7 seeded from xg ----
        f32x4 acc[4];
        #pragma unroll
        for (int nt = 0; nt < 4; ++nt)
            acc[nt] = xlive ? cvtxg(xgc[nt]) : (f32x4){0.f,0.f,0.f,0.f};
        if (t > 0) {
            #pragma unroll
            for (int kt = 0; kt < 16; ++kt) {
                bf16x8 a = *(const bf16x8*)&h_lds[cl][(kt*32 + kgrp*8) ^ ((cl & 7) << 3)];
                #pragma unroll
                for (int nt = 0; nt < 4; ++nt)
                    acc[nt] = __builtin_amdgcn_mfma_f32_16x16x32_bf16(a, whf[kt][nt], acc[nt], 0, 0, 0);
            }
        }

        // ---- preactivations: only live rows 0..7 (kgrp<2) ----
        if (xlive) {
            #pragma unroll
            for (int nt = 0; nt < 4; ++nt)
                #pragma unroll
                for (int r = 0; r < 4; ++r)
                    P_lds[kgrp*4 + r][wv*64 + nt*16 + cl] = acc[nt][r];
        }
        bar_lds();   // B2: P visible (DS-only drain)

        // ---- activations: thread owns (batch sb, units 2*sc, 2*sc+1) ----
        {
            float4 g0 = *(const float4*)&P_lds[sb][sc*8];
            float4 g1 = *(const float4*)&P_lds[sb][sc*8 + 4];
            float r0 = sigf(g0.x), f0 = sigf(g0.y), z0 = tanhfast(g0.z), o0 = sigf(g0.w);
            float r1 = sigf(g1.x), f1 = sigf(g1.y), z1 = tanhfast(g1.z), o1 = sigf(g1.w);
            c0 = f0*c0 + r0*z0;
            c1 = f1*c1 + r1*z1;
            float h0 = o0*tanhfast(c0);
            float h1 = o1*tanhfast(c1);
            if (t == TB - 1) {
                float2 hw = { h0, h1 };
                *(float2*)&out[64 + (size_t)(g*DB + sb)*HH + ug*64 + 2*sc] = hw;
            }
            // dual publish: tagged u64, fast (sc0) + slow (agent atomic)
            u64 v = (((u64)(u32)(t + 1)) << 32)
                  | (u64)(bfbits(h0) | (bfbits(h1) << 16));
            size_t di = ((size_t)(t & 1))*NB*NPAIR
                      + (size_t)(g*DB + sb)*NPAIR + ug*32 + sc;
            asm volatile("global_store_dwordx2 %0, %1, off sc0"
                         :: "v"((u64)(fastH + di)), "v"(v) : "memory");
            __hip_atomic_store(slowH + di, v, __ATOMIC_RELAXED, __HIP_MEMORY_SCOPE_AGENT);
        }
        #pragma unroll
        for (int nt = 0; nt < 4; ++nt) xgc[nt] = xgn[nt];
        // no end-of-step barrier, no flag, no fence
    }

    // ---- final FC head: block ug==0 of each domain ----
    if (ug == 0) {
        size_t off = ((size_t)((TB - 1) & 1))*NB*NPAIR
                   + (size_t)(g*DB + sb)*NPAIR + sc*8;
        u64 pk[4];
        poll8_dual(fastH + off, slowH + off, (u32)TB, pk);
        float s = 0.f;
        const float4* wp = (const float4*)(Wfc + sc*16);
        #pragma unroll
        for (int k = 0; k < 4; ++k) {
            float4 w = wp[k];
            u64 p = pk[k];
            s += __uint_as_float((u32)( p        & 0xFFFFu) << 16) * w.x;
            s += __uint_as_float((u32)((p >> 16) & 0xFFFFu) << 16) * w.y;
            s += __uint_as_float((u32)((p >> 32) & 0xFFFFu) << 16) * w.z;
            s += __uint_as_float((u32)((p >> 48) & 0xFFFFu) << 16) * w.w;
        }
        __syncthreads();   // all act-phase P_lds reads done
        P_lds[sb][sc] = s;
        __syncthreads();
        if (tid < 8) {
            float acc = 0.f;
            #pragma unroll
            for (int q = 0; q < 32; ++q) acc += P_lds[tid][q];
            out[g*DB + tid] = sigf(acc + bfc[0]);
        }
    }
}

extern "C" void kernel_launch(void* const* d_in, const int* in_sizes, int n_in,
                              void* d_out, int out_size, void* d_ws, size_t ws_size,
                              hipStream_t stream) {
    (void)in_sizes; (void)n_in; (void)out_size; (void)ws_size;
    const int*   words = (const int*)d_in[0];
    const float* emb   = (const float*)d_in[1];
    const float* Wi    = (const float*)d_in[2];
    const float* bi    = (const float*)d_in[3];
    const float* Wh    = (const float*)d_in[4];
    const float* bh    = (const float*)d_in[5];
    const float* Wfc   = (const float*)d_in[6];
    const float* bfc   = (const float*)d_in[7];
    float* out = (float*)d_out;

    u64* fastH  = (u64*)d_ws;
    u64* slowH  = (u64*)((char*)d_ws + SLOWOFF);
    bf16_t* xgT = (bf16_t*)((char*)d_ws + XGOFF);

    // zero both tag buffers every launch (tag 0 matches no step)
    hipMemsetAsync(d_ws, 0, 2*SLOWOFF, stream);

    xg_prepass<<<dim3(256), dim3(256), 0, stream>>>(words, emb, Wi, bi, bh, xgT);
    lstm_main<<<dim3(ND*NBLK), dim3(NT), 0, stream>>>(Wh, Wfc, bfc, out,
                                                      fastH, slowH, (const u64*)xgT);
}

// Round 11
// 2143.819 us; speedup vs baseline: 1.0321x; 1.0321x over previous
//
#include <hip/hip_runtime.h>
#include <hip/hip_bf16.h>

// LSTM: B=64, T=512, V=32000, E=256, H=512, O=1
// R11 = R9 verbatim with exactly two changes:
//  (1) domain = blockIdx>>3 (8 CONSECUTIVE blocks per sync domain; tests the
//      chunked workgroup->XCD placement hypothesis — R9/R10 showed the
//      interleaved blockIdx&7 grouping is NOT co-XCD: fast sc0 path dead),
//  (2) slow-probe cadence 4 -> 2 (R9 vs R10 showed detection latency tracks
//      probe interval while the fast path misses).
// Dual-protocol tagged exchange: every h-pair u64 (tag<<32 | 2xbf16) stored
// both sc0 (L2-fast if co-XCD) and agent-scope (MALL, always visible).
#define TB 512
#define NB 64
#define EE 256
#define HH 512
#define ND 8           // sync domains
#define DB 8           // batches per domain
#define NBLK 8         // blocks per domain
#define NT 256         // threads per block (4 waves)
#define NCOLP 260      // P_lds padded row (floats)
#define NPAIR 256      // h pairs per batch
#define GCOLS 2048
#define SLOWOFF ((size_t)0x40000)  // slow buffer offset (fast at 0, 256KB each)
#define XGOFF   ((size_t)1 << 20)  // xg offset in d_ws

typedef __bf16 bf16_t;
typedef bf16_t bf16x8 __attribute__((ext_vector_type(8)));
typedef float  f32x4  __attribute__((ext_vector_type(4)));
typedef unsigned u32;
typedef unsigned long long u64;
typedef u32 u32x4 __attribute__((ext_vector_type(4)));

__device__ __forceinline__ float sigf(float x) { return 1.0f / (1.0f + __expf(-x)); }
__device__ __forceinline__ float tanhfast(float x) {
    float xc = fminf(fmaxf(x, -15.0f), 15.0f);
    float e  = __expf(2.0f * xc);
    return (e - 1.0f) / (e + 1.0f);
}
__device__ __forceinline__ u32 bfbits(float f) {
    bf16_t h = (bf16_t)f;
    return (u32)__builtin_bit_cast(unsigned short, h);
}
__device__ __forceinline__ bf16x8 cvt8(float4 a, float4 b) {
    bf16x8 v;
    v[0]=(bf16_t)a.x; v[1]=(bf16_t)a.y; v[2]=(bf16_t)a.z; v[3]=(bf16_t)a.w;
    v[4]=(bf16_t)b.x; v[5]=(bf16_t)b.y; v[6]=(bf16_t)b.z; v[7]=(bf16_t)b.w;
    return v;
}
__device__ __forceinline__ f32x4 cvtxg(u64 v) {
    f32x4 r;
    r[0] = __uint_as_float((u32)( v        & 0xFFFFu) << 16);
    r[1] = __uint_as_float((u32)((v >> 16) & 0xFFFFu) << 16);
    r[2] = __uint_as_float((u32)((v >> 32) & 0xFFFFu) << 16);
    r[3] = __uint_as_float((u32)((v >> 48) & 0xFFFFu) << 16);
    return r;
}

// Dual poll of 8 tagged u64s (64B): hot-spin sc0 (L2), slow probe every 2nd.
__device__ __forceinline__ void poll8_dual(const u64* fsrc, const u64* ssrc,
                                           u32 tag, u64 (&pk)[4]) {
    u64 fa = (u64)fsrc;
    int it = 0;
    for (;;) {
        u32x4 q0, q1, q2, q3;
        asm volatile(
            "global_load_dwordx4 %0, %4, off sc0\n\t"
            "global_load_dwordx4 %1, %4, off offset:16 sc0\n\t"
            "global_load_dwordx4 %2, %4, off offset:32 sc0\n\t"
            "global_load_dwordx4 %3, %4, off offset:48 sc0\n\t"
            "s_waitcnt vmcnt(0)"
            : "=&v"(q0), "=&v"(q1), "=&v"(q2), "=&v"(q3)
            : "v"(fa)
            : "memory");
        if (q0[1]==tag && q0[3]==tag && q1[1]==tag && q1[3]==tag &&
            q2[1]==tag && q2[3]==tag && q3[1]==tag && q3[3]==tag) {
            pk[0] = (u64)q0[0] | ((u64)q0[2] << 32);
            pk[1] = (u64)q1[0] | ((u64)q1[2] << 32);
            pk[2] = (u64)q2[0] | ((u64)q2[2] << 32);
            pk[3] = (u64)q3[0] | ((u64)q3[2] << 32);
            return;
        }
        if (((++it) & 1) == 0) {
            u64 hv[8];
            #pragma unroll
            for (int j = 0; j < 8; ++j)
                hv[j] = __hip_atomic_load(ssrc + j, __ATOMIC_RELAXED, __HIP_MEMORY_SCOPE_AGENT);
            bool ok = true;
            #pragma unroll
            for (int j = 0; j < 8; ++j) ok &= ((u32)(hv[j] >> 32) == tag);
            if (ok) {
                #pragma unroll
                for (int k = 0; k < 4; ++k)
                    pk[k] = (u64)(u32)hv[2*k] | ((u64)(u32)hv[2*k + 1] << 32);
                return;
            }
        }
    }
}

// ---------------- Phase 1: xg pre-pass GEMM (proven R7, verbatim) ----------------
__global__ __launch_bounds__(256, 1)
void xg_prepass(const int* __restrict__ words, const float* __restrict__ emb,
                const float* __restrict__ Wi, const float* __restrict__ bi,
                const float* __restrict__ bh, bf16_t* __restrict__ xgT)
{
    const int tid = threadIdx.x, lane = tid & 63, wv = tid >> 6;
    const int kgrp = lane >> 4, cl = lane & 15;
    const int cc = blockIdx.x & 7, tc = blockIdx.x >> 3;

    __shared__ __align__(16) bf16_t x_s[64][EE];

    bf16x8 wf[8][4];
    float  bv[4];
    #pragma unroll
    for (int nt = 0; nt < 4; ++nt) {
        int col = cc*256 + wv*64 + nt*16 + cl;
        int wrow = (col & 3)*HH + (col >> 2);
        const float* wr = Wi + (size_t)wrow*EE;
        #pragma unroll
        for (int kt = 0; kt < 8; ++kt) {
            const float4* p = (const float4*)(wr + kt*32 + kgrp*8);
            wf[kt][nt] = cvt8(p[0], p[1]);
        }
        bv[nt] = bi[wrow] + bh[wrow];
    }

    const int r0 = tid >> 2, q = tid & 3;
    const int swz = (r0 & 7) << 3;
    u64* dst = (u64*)xgT;

    for (int it = 0; it < 16; ++it) {
        int t = tc*16 + it;
        {
            int wd = words[r0*TB + t];
            const float4* p = (const float4*)(emb + (size_t)wd*EE + q*64);
            #pragma unroll
            for (int o = 0; o < 8; ++o) {
                float4 a = p[2*o], b2 = p[2*o + 1];
                *(bf16x8*)&x_s[r0][(q*64 + o*8) ^ swz] = cvt8(a, b2);
            }
        }
        __syncthreads();

        f32x4 acc[4][4];
        #pragma unroll
        for (int rt = 0; rt < 4; ++rt)
            #pragma unroll
            for (int nt = 0; nt < 4; ++nt)
                acc[rt][nt] = (f32x4){ bv[nt], bv[nt], bv[nt], bv[nt] };
        #pragma unroll
        for (int kt = 0; kt < 8; ++kt) {
            #pragma unroll
            for (int rt = 0; rt < 4; ++rt) {
                bf16x8 a = *(const bf16x8*)&x_s[rt*16 + cl][(kt*32 + kgrp*8) ^ ((cl & 7) << 3)];
                #pragma unroll
                for (int nt = 0; nt < 4; ++nt)
                    acc[rt][nt] = __builtin_amdgcn_mfma_f32_16x16x32_bf16(a, wf[kt][nt], acc[rt][nt], 0, 0, 0);
            }
        }
        #pragma unroll
        for (int nt = 0; nt < 4; ++nt) {
            int col = cc*256 + wv*64 + nt*16 + cl;
            #pragma unroll
            for (int rt = 0; rt < 4; ++rt) {
                f32x4 v = acc[rt][nt];
                u64 pkk =  (u64)(bfbits(v[0]))
                        | ((u64)(bfbits(v[1])) << 16)
                        | ((u64)(bfbits(v[2])) << 32)
                        | ((u64)(bfbits(v[3])) << 48);
                dst[(size_t)(t*GCOLS + col)*16 + rt*4 + kgrp] = pkk;
            }
        }
        __syncthreads();
    }
}

// ---------------- Phase 2: persistent recurrence, dual-protocol exchange ----------------
__global__ __launch_bounds__(NT, 1)
void lstm_main(const float* __restrict__ Wh,
               const float* __restrict__ Wfc,
               const float* __restrict__ bfc,
               float* __restrict__ out,        // [64] head + [64*512] h (fp32)
               u64* __restrict__ fastH,        // [2][NB][NPAIR] tagged pairs (sc0)
               u64* __restrict__ slowH,        // [2][NB][NPAIR] tagged pairs (agent)
               const u64* __restrict__ xg64)   // xg[t][col][batchquad]
{
    const int tid  = threadIdx.x;
    const int lane = tid & 63;
    const int wv   = tid >> 6;        // 0..3
    const int g    = blockIdx.x >> 3; // domain = 8 CONSECUTIVE blocks (R11 change)
    const int ug   = blockIdx.x & 7;  // unit group 0..7 (64 units each)
    const int kgrp = lane >> 4;
    const int cl   = lane & 15;

    __shared__ __align__(16) bf16_t h_lds[16][HH];    // rows 8..15 stay zero
    __shared__ __align__(16) float  P_lds[16][NCOLP];

    // zero h_lds (h_{-1}=0)
    for (int i = tid; i < 16*HH/2; i += NT) ((u32*)h_lds)[i] = 0u;

    // ---- Wh fragments: 4 n-tiles per wave (256 local cols per block) ----
    bf16x8 whf[16][4];
    #pragma unroll
    for (int nt = 0; nt < 4; ++nt) {
        int gc = ug*256 + wv*64 + nt*16 + cl;       // global gate-col
        int wrow = (gc & 3)*HH + (gc >> 2);
        const float* wr = Wh + (size_t)wrow*HH;
        #pragma unroll
        for (int kt = 0; kt < 16; ++kt) {
            const float4* p = (const float4*)(wr + kt*32 + kgrp*8);
            whf[kt][nt] = cvt8(p[0], p[1]);
        }
    }

    // thread roles for poll/act: batch sb (0..7), chunk sc (0..31)
    const int sb = tid >> 5, sc = tid & 31;
    const int swz = sb << 3;

    // xg addressing: quad m covers batches 4m..4m+3; local rows kgrp*4+r
    const int m = 2*g + (kgrp & 1);
    int gc[4];
    #pragma unroll
    for (int nt = 0; nt < 4; ++nt) gc[nt] = ug*256 + wv*64 + nt*16 + cl;

    u64 xgc[4], xgn[4];
    #pragma unroll
    for (int nt = 0; nt < 4; ++nt) xgc[nt] = xg64[(size_t)gc[nt]*16 + m];

    float c0 = 0.f, c1 = 0.f;
    __syncthreads();

    for (int t = 0; t < TB; ++t) {
        // ---- poll tagged h_{t-1} (8 pairs from one producer), stage to LDS ----
        if (t > 0) {
            size_t off = ((size_t)((t & 1) ^ 1))*NB*NPAIR
                       + (size_t)(g*DB + sb)*NPAIR + sc*8;
            u64 pk[4];
            poll8_dual(fastH + off, slowH + off, (u32)t, pk);
            #pragma unroll
            for (int k = 0; k < 4; ++k) {
                int e = sc*16 + 4*k;
                int phys = ((e & ~7) ^ swz) | (e & 7);
                *(u64*)&h_lds[sb][phys] = pk[k];
            }
        }

        // ---- prefetch xg(t+1): sequential, one full step of slack ----
        if (t + 1 < TB) {
            #pragma unroll
            for (int nt = 0; nt < 4; ++nt)
                xgn[nt] = xg64[(size_t)((t + 1)*GCOLS + gc[nt])*16 + m];
        }
        __syncthreads();   // B1: h_lds visible

        // ---- recurrent MFMAs, acc seeded from xg (bias pre-folded) ----
        f32x4 acc[4];
        #pragma unroll
        for (int nt = 0; nt < 4; ++nt) acc[nt] = cvtxg(xgc[nt]);
        if (t > 0) {
            #pragma unroll
            for (int kt = 0; kt < 16; ++kt) {
                bf16x8 a = *(const bf16x8*)&h_lds[cl][(kt*32 + kgrp*8) ^ ((cl & 7) << 3)];
                #pragma unroll
                for (int nt = 0; nt < 4; ++nt)
                    acc[nt] = __builtin_amdgcn_mfma_f32_16x16x32_bf16(a, whf[kt][nt], acc[nt], 0, 0, 0);
            }
        }

        // ---- preactivations: row = kgrp*4+r (local batch), col = local gate-col ----
        #pragma unroll
        for (int nt = 0; nt < 4; ++nt)
            #pragma unroll
            for (int r = 0; r < 4; ++r)
                P_lds[kgrp*4 + r][wv*64 + nt*16 + cl] = acc[nt][r];
        __syncthreads();   // B2: P visible

        // ---- activations: thread owns (batch sb, units 2*sc, 2*sc+1) ----
        {
            float4 g0 = *(const float4*)&P_lds[sb][sc*8];
            float4 g1 = *(const float4*)&P_lds[sb][sc*8 + 4];
            float r0 = sigf(g0.x), f0 = sigf(g0.y), z0 = tanhfast(g0.z), o0 = sigf(g0.w);
            float r1 = sigf(g1.x), f1 = sigf(g1.y), z1 = tanhfast(g1.z), o1 = sigf(g1.w);
            c0 = f0*c0 + r0*z0;
            c1 = f1*c1 + r1*z1;
            float h0 = o0*tanhfast(c0);
            float h1 = o1*tanhfast(c1);
            if (t == TB - 1) {
                float2 hw = { h0, h1 };
                *(float2*)&out[64 + (size_t)(g*DB + sb)*HH + ug*64 + 2*sc] = hw;
            }
            // dual publish: tagged u64, fast (sc0) + slow (agent atomic)
            u64 v = (((u64)(u32)(t + 1)) << 32)
                  | (u64)(bfbits(h0) | (bfbits(h1) << 16));
            size_t di = ((size_t)(t & 1))*NB*NPAIR
                      + (size_t)(g*DB + sb)*NPAIR + ug*32 + sc;
            asm volatile("global_store_dwordx2 %0, %1, off sc0"
                         :: "v"((u64)(fastH + di)), "v"(v) : "memory");
            __hip_atomic_store(slowH + di, v, __ATOMIC_RELAXED, __HIP_MEMORY_SCOPE_AGENT);
        }
        #pragma unroll
        for (int nt = 0; nt < 4; ++nt) xgc[nt] = xgn[nt];
        // no end-of-step barrier, no flag, no fence
    }

    // ---- final FC head: block ug==0 of each domain ----
    if (ug == 0) {
        size_t off = ((size_t)((TB - 1) & 1))*NB*NPAIR
                   + (size_t)(g*DB + sb)*NPAIR + sc*8;
        u64 pk[4];
        poll8_dual(fastH + off, slowH + off, (u32)TB, pk);
        float s = 0.f;
        const float4* wp = (const float4*)(Wfc + sc*16);
        #pragma unroll
        for (int k = 0; k < 4; ++k) {
            float4 w = wp[k];
            u64 p = pk[k];
            s += __uint_as_float((u32)( p        & 0xFFFFu) << 16) * w.x;
            s += __uint_as_float((u32)((p >> 16) & 0xFFFFu) << 16) * w.y;
            s += __uint_as_float((u32)((p >> 32) & 0xFFFFu) << 16) * w.z;
            s += __uint_as_float((u32)((p >> 48) & 0xFFFFu) << 16) * w.w;
        }
        __syncthreads();   // all act-phase P_lds reads done
        P_lds[sb][sc] = s;
        __syncthreads();
        if (tid < 8) {
            float acc = 0.f;
            #pragma unroll
            for (int q = 0; q < 32; ++q) acc += P_lds[tid][q];
            out[g*DB + tid] = sigf(acc + bfc[0]);
        }
    }
}

extern "C" void kernel_launch(void* const* d_in, const int* in_sizes, int n_in,
                              void* d_out, int out_size, void* d_ws, size_t ws_size,
                              hipStream_t stream) {
    (void)in_sizes; (void)n_in; (void)out_size; (void)ws_size;
    const int*   words = (const int*)d_in[0];
    const float* emb   = (const float*)d_in[1];
    const float* Wi    = (const float*)d_in[2];
    const float* bi    = (const float*)d_in[3];
    const float* Wh    = (const float*)d_in[4];
    const float* bh    = (const float*)d_in[5];
    const float* Wfc   = (const float*)d_in[6];
    const float* bfc   = (const float*)d_in[7];
    float* out = (float*)d_out;

    u64* fastH  = (u64*)d_ws;
    u64* slowH  = (u64*)((char*)d_ws + SLOWOFF);
    bf16_t* xgT = (bf16_t*)((char*)d_ws + XGOFF);

    // zero both tag buffers every launch (tag 0 matches no step)
    hipMemsetAsync(d_ws, 0, 2*SLOWOFF, stream);

    xg_prepass<<<dim3(256), dim3(256), 0, stream>>>(words, emb, Wi, bi, bh, xgT);
    lstm_main<<<dim3(ND*NBLK), dim3(NT), 0, stream>>>(Wh, Wfc, bfc, out,
                                                      fastH, slowH, (const u64*)xgT);
}